// Round 1
// baseline (17382.582 us; speedup 1.0000x reference)
//
#include <hip/hip_runtime.h>
#include <math.h>

#define L_LAYERS 12
#define H_HEADS  12
#define F_DIM    768
#define FH_DIM   64
#define MLPD     3072
#define NT       1025          // 1 + 32*32 tokens
#define THREE_F  2304
#define R_REL    3972          // (2*32-1)^2 + 3
#define QK_SCALE 0.125f        // 64^-0.5

// ---------------------------------------------------------------- init x ----
__global__ void init_x_k(const float* __restrict__ patch, const float* __restrict__ cls,
                         float* __restrict__ x) {
    int i = blockIdx.x * 256 + threadIdx.x;
    if (i >= NT * F_DIM) return;
    int n = i / F_DIM, f = i - n * F_DIM;
    x[i] = (n == 0) ? cls[f] : patch[(size_t)(n - 1) * F_DIM + f];
}

// -------------------------------------------------------------- layernorm ----
__global__ void layernorm_k(const float* __restrict__ x, const float* __restrict__ w,
                            const float* __restrict__ b, float* __restrict__ out) {
    const int row = blockIdx.x;
    const float* xr = x + (size_t)row * F_DIM;
    float v0 = xr[threadIdx.x];
    float v1 = xr[threadIdx.x + 256];
    float v2 = xr[threadIdx.x + 512];
    float s  = v0 + v1 + v2;
    float s2 = v0 * v0 + v1 * v1 + v2 * v2;
    #pragma unroll
    for (int off = 32; off; off >>= 1) {
        s  += __shfl_down(s, off);
        s2 += __shfl_down(s2, off);
    }
    __shared__ float ws_[4], ws2_[4];
    int lane = threadIdx.x & 63, wid = threadIdx.x >> 6;
    if (lane == 0) { ws_[wid] = s; ws2_[wid] = s2; }
    __syncthreads();
    float S  = ws_[0] + ws_[1] + ws_[2] + ws_[3];
    float S2 = ws2_[0] + ws2_[1] + ws2_[2] + ws2_[3];
    float mu  = S * (1.0f / F_DIM);
    float var = S2 * (1.0f / F_DIM) - mu * mu;
    float rs  = rsqrtf(var + 1e-6f);
    float* orow = out + (size_t)row * F_DIM;
    orow[threadIdx.x]       = (v0 - mu) * rs * w[threadIdx.x]       + b[threadIdx.x];
    orow[threadIdx.x + 256] = (v1 - mu) * rs * w[threadIdx.x + 256] + b[threadIdx.x + 256];
    orow[threadIdx.x + 512] = (v2 - mu) * rs * w[threadIdx.x + 512] + b[threadIdx.x + 512];
}

// ---------------------------------------------------------------- GEMM NT ----
// C[m][n] = sum_k A[m][k] * B[n][k]   (A: MxK row-major, B: NcxK row-major)
// EPI 0: C = acc
// EPI 1: C = gelu(acc + bias)
// EPI 2: C = resid + scale * (acc + bias)   (resid may alias C)
#define BM 64
#define BN 64
#define BK 32

template <int EPI>
__global__ void gemm_nt_k(const float* __restrict__ A, const float* __restrict__ B,
                          const float* __restrict__ bias, const float* __restrict__ scale,
                          const float* __restrict__ resid, float* __restrict__ C,
                          int M, int Nc, int K) {
    __shared__ float As[BM][BK + 1];
    __shared__ float Bs[BN][BK + 1];
    const int bm = blockIdx.x * BM;
    const int bn = blockIdx.y * BN;
    const int tid = threadIdx.x;
    const int tx = tid & 15, ty = tid >> 4;
    float acc[4][4] = {};
    for (int k0 = 0; k0 < K; k0 += BK) {
        #pragma unroll
        for (int i = 0; i < 8; ++i) {
            int idx = tid + i * 256;
            int r = idx >> 5, c = idx & 31;
            int gr = bm + r;
            As[r][c] = (gr < M) ? A[(size_t)gr * K + (k0 + c)] : 0.0f;
            int gr2 = bn + r;
            Bs[r][c] = (gr2 < Nc) ? B[(size_t)gr2 * K + (k0 + c)] : 0.0f;
        }
        __syncthreads();
        #pragma unroll
        for (int kk = 0; kk < BK; ++kk) {
            float a[4], b[4];
            #pragma unroll
            for (int i = 0; i < 4; ++i) a[i] = As[ty * 4 + i][kk];
            #pragma unroll
            for (int j = 0; j < 4; ++j) b[j] = Bs[tx * 4 + j][kk];
            #pragma unroll
            for (int i = 0; i < 4; ++i)
                #pragma unroll
                for (int j = 0; j < 4; ++j)
                    acc[i][j] += a[i] * b[j];
        }
        __syncthreads();
    }
    #pragma unroll
    for (int i = 0; i < 4; ++i) {
        int gr = bm + ty * 4 + i;
        if (gr >= M) continue;
        #pragma unroll
        for (int j = 0; j < 4; ++j) {
            int gc = bn + tx * 4 + j;
            if (gc >= Nc) continue;
            float v = acc[i][j];
            size_t oi = (size_t)gr * Nc + gc;
            if (EPI == 0) {
                C[oi] = v;
            } else if (EPI == 1) {
                v += bias[gc];
                C[oi] = 0.5f * v * (1.0f + erff(v * 0.70710678118654752f));
            } else {
                v += bias[gc];
                C[oi] = resid[oi] + scale[gc] * v;
            }
        }
    }
}

// ------------------------------------------------------------- QK^T + bias ---
__global__ void qk_attn_k(const float* __restrict__ qkv, const float* __restrict__ q_bias,
                          const float* __restrict__ table, const int* __restrict__ rp_idx,
                          float* __restrict__ attn) {
    const int h  = blockIdx.z;
    const int n0 = blockIdx.y * 16, m0 = blockIdx.x * 16;
    __shared__ float qs[16][65], ks[16][65];
    const int tid = threadIdx.x;
    #pragma unroll
    for (int i = 0; i < 4; ++i) {
        int idx = tid + i * 256;
        int r = idx >> 6, d = idx & 63;
        int n = n0 + r, m = m0 + r;
        float qv = 0.0f, kv = 0.0f;
        if (n < NT) qv = (qkv[(size_t)n * THREE_F + h * 64 + d] + q_bias[h * 64 + d]) * QK_SCALE;
        if (m < NT) kv = qkv[(size_t)m * THREE_F + F_DIM + h * 64 + d];
        qs[r][d] = qv;
        ks[r][d] = kv;
    }
    __syncthreads();
    const int tx = tid & 15, ty = tid >> 4;
    const int n = n0 + ty, m = m0 + tx;
    if (n < NT && m < NT) {
        float s = 0.0f;
        #pragma unroll
        for (int d = 0; d < 64; ++d) s += qs[ty][d] * ks[tx][d];
        int idx = rp_idx[(size_t)n * NT + m];
        s += table[(size_t)idx * H_HEADS + h];
        attn[((size_t)h * NT + n) * NT + m] = s;
    }
}

// ----------------------------------------------------------------- softmax ---
__global__ void softmax_k(float* __restrict__ attn) {
    float* a = attn + (size_t)blockIdx.x * NT;
    float vals[5];
    float m = -1e30f;
    #pragma unroll
    for (int i = 0; i < 5; ++i) {
        int c = threadIdx.x + i * 256;
        vals[i] = (c < NT) ? a[c] : -1e30f;
        m = fmaxf(m, vals[i]);
    }
    #pragma unroll
    for (int off = 32; off; off >>= 1) m = fmaxf(m, __shfl_down(m, off));
    __shared__ float red[4];
    int lane = threadIdx.x & 63, wid = threadIdx.x >> 6;
    if (lane == 0) red[wid] = m;
    __syncthreads();
    m = fmaxf(fmaxf(red[0], red[1]), fmaxf(red[2], red[3]));
    float s = 0.0f;
    #pragma unroll
    for (int i = 0; i < 5; ++i) {
        int c = threadIdx.x + i * 256;
        if (c < NT) { vals[i] = __expf(vals[i] - m); s += vals[i]; }
    }
    #pragma unroll
    for (int off = 32; off; off >>= 1) s += __shfl_down(s, off);
    __syncthreads();
    if (lane == 0) red[wid] = s;
    __syncthreads();
    s = red[0] + red[1] + red[2] + red[3];
    float inv = 1.0f / s;
    #pragma unroll
    for (int i = 0; i < 5; ++i) {
        int c = threadIdx.x + i * 256;
        if (c < NT) a[c] = vals[i] * inv;
    }
}

// --------------------------------------------------------------------- PV ----
// o[n][h*64+d] = sum_m attn[h][n][m] * (v[m][d] + v_bias[h][d])
__global__ void pv_k(const float* __restrict__ attn, const float* __restrict__ qkv,
                     const float* __restrict__ v_bias, float* __restrict__ o) {
    const int h  = blockIdx.y;
    const int n0 = blockIdx.x * 64;
    __shared__ float Ps[64][17], Vs[16][65];
    const int tid = threadIdx.x;
    const int tx = tid & 15, ty = tid >> 4;
    float acc[4][4] = {};
    for (int m0 = 0; m0 < NT; m0 += 16) {
        #pragma unroll
        for (int i = 0; i < 4; ++i) {
            int idx = tid + i * 256;
            int r = idx >> 4, c = idx & 15;
            int n = n0 + r, m = m0 + c;
            Ps[r][c] = (n < NT && m < NT) ? attn[((size_t)h * NT + n) * NT + m] : 0.0f;
        }
        #pragma unroll
        for (int i = 0; i < 4; ++i) {
            int idx = tid + i * 256;
            int r = idx >> 6, d = idx & 63;
            int m = m0 + r;
            Vs[r][d] = (m < NT) ? (qkv[(size_t)m * THREE_F + 2 * F_DIM + h * 64 + d] + v_bias[h * 64 + d])
                                : 0.0f;
        }
        __syncthreads();
        #pragma unroll
        for (int kk = 0; kk < 16; ++kk) {
            float a[4], b[4];
            #pragma unroll
            for (int i = 0; i < 4; ++i) a[i] = Ps[ty * 4 + i][kk];
            #pragma unroll
            for (int j = 0; j < 4; ++j) b[j] = Vs[kk][tx * 4 + j];
            #pragma unroll
            for (int i = 0; i < 4; ++i)
                #pragma unroll
                for (int j = 0; j < 4; ++j)
                    acc[i][j] += a[i] * b[j];
        }
        __syncthreads();
    }
    #pragma unroll
    for (int i = 0; i < 4; ++i) {
        int n = n0 + ty * 4 + i;
        if (n >= NT) continue;
        #pragma unroll
        for (int j = 0; j < 4; ++j) {
            o[(size_t)n * F_DIM + h * 64 + tx * 4 + j] = acc[i][j];
        }
    }
}

// ------------------------------------------------------------------- host ----
extern "C" void kernel_launch(void* const* d_in, const int* in_sizes, int n_in,
                              void* d_out, int out_size, void* d_ws, size_t ws_size,
                              hipStream_t stream) {
    const float* patch      = (const float*)d_in[0];
    const float* cls        = (const float*)d_in[1];
    const float* ln1_w      = (const float*)d_in[2];
    const float* ln1_b      = (const float*)d_in[3];
    const float* qkv_w      = (const float*)d_in[4];
    const float* q_bias     = (const float*)d_in[5];
    const float* v_bias     = (const float*)d_in[6];
    const float* proj_w     = (const float*)d_in[7];
    const float* proj_b     = (const float*)d_in[8];
    const float* scale_attn = (const float*)d_in[9];
    const float* ln2_w      = (const float*)d_in[10];
    const float* ln2_b      = (const float*)d_in[11];
    const float* fc1_w      = (const float*)d_in[12];
    const float* fc1_b      = (const float*)d_in[13];
    const float* fc2_w      = (const float*)d_in[14];
    const float* fc2_b      = (const float*)d_in[15];
    const float* scale_mlp  = (const float*)d_in[16];
    const float* table      = (const float*)d_in[17];
    const int*   rp_idx     = (const int*)d_in[18];
    float* out = (float*)d_out;

    float* ws = (float*)d_ws;
    size_t off = 0;
    float* x    = ws + off; off += (size_t)NT * F_DIM;
    float* h    = ws + off; off += (size_t)NT * F_DIM;
    float* qkvb = ws + off; off += (size_t)NT * THREE_F;
    float* attn = ws + off; off += (size_t)H_HEADS * NT * NT;
    float* o    = ws + off; off += (size_t)NT * F_DIM;
    float* m1   = ws + off; off += (size_t)NT * MLPD;

    init_x_k<<<(NT * F_DIM + 255) / 256, 256, 0, stream>>>(patch, cls, x);

    int stage = 0;
    for (int l = 0; l < L_LAYERS; ++l) {
        layernorm_k<<<NT, 256, 0, stream>>>(x, ln1_w + l * F_DIM, ln1_b + l * F_DIM, h);

        gemm_nt_k<0><<<dim3(17, 36), 256, 0, stream>>>(
            h, qkv_w + (size_t)l * THREE_F * F_DIM, nullptr, nullptr, nullptr, qkvb,
            NT, THREE_F, F_DIM);

        qk_attn_k<<<dim3(65, 65, H_HEADS), 256, 0, stream>>>(
            qkvb, q_bias + l * F_DIM, table + (size_t)l * R_REL * H_HEADS, rp_idx, attn);

        softmax_k<<<H_HEADS * NT, 256, 0, stream>>>(attn);

        pv_k<<<dim3(17, H_HEADS), 256, 0, stream>>>(attn, qkvb, v_bias + l * F_DIM, o);

        gemm_nt_k<2><<<dim3(17, 12), 256, 0, stream>>>(
            o, proj_w + (size_t)l * F_DIM * F_DIM, proj_b + l * F_DIM,
            scale_attn + l * F_DIM, x, x, NT, F_DIM, F_DIM);

        layernorm_k<<<NT, 256, 0, stream>>>(x, ln2_w + l * F_DIM, ln2_b + l * F_DIM, h);

        gemm_nt_k<1><<<dim3(17, 48), 256, 0, stream>>>(
            h, fc1_w + (size_t)l * MLPD * F_DIM, fc1_b + l * MLPD, nullptr, nullptr, m1,
            NT, MLPD, F_DIM);

        gemm_nt_k<2><<<dim3(17, 12), 256, 0, stream>>>(
            m1, fc2_w + (size_t)l * F_DIM * MLPD, fc2_b + l * F_DIM,
            scale_mlp + l * F_DIM, x, x, NT, F_DIM, MLPD);

        if (l == 2 || l == 5 || l == 8 || l == 11) {
            hipMemcpyAsync(out + (size_t)stage * NT * F_DIM, x,
                           (size_t)NT * F_DIM * sizeof(float),
                           hipMemcpyDeviceToDevice, stream);
            ++stage;
        }
    }
}

// Round 3
// 3582.005 us; speedup vs baseline: 4.8528x; 4.8528x over previous
//
#include <hip/hip_runtime.h>
#include <hip/hip_bf16.h>
#include <math.h>

#define L_LAYERS 12
#define H_HEADS  12
#define F_DIM    768
#define FH_DIM   64
#define MLPD     3072
#define NT       1025          // 1 + 32*32 tokens
#define NTP      1056          // NT padded to multiple of 32 (zero tail)
#define THREE_F  2304
#define R_REL    3972
#define QK_SCALE 0.125f

typedef short short8_t __attribute__((ext_vector_type(8)));
typedef float f32x4_t  __attribute__((ext_vector_type(4)));
typedef __attribute__((address_space(1))) const void* gptr_t;
typedef __attribute__((address_space(3))) void*       lptr_t;

typedef __hip_bfloat16 bf16;

static __device__ inline unsigned short f2bf(float f) {
    __hip_bfloat16 b(f);
    unsigned short u;
    __builtin_memcpy(&u, &b, 2);
    return u;
}

// ---------------------------------------------------------------- init x ----
__global__ void init_x_k(const float* __restrict__ patch, const float* __restrict__ cls,
                         float* __restrict__ x) {
    int i = blockIdx.x * 256 + threadIdx.x;
    if (i >= NT * F_DIM) return;
    int n = i / F_DIM, f = i - n * F_DIM;
    x[i] = (n == 0) ? cls[f] : patch[(size_t)(n - 1) * F_DIM + f];
}

// ----------------------------------------------------------- zero vT tail ----
__global__ void zero_vt_k(bf16* __restrict__ vt) {
    int i = blockIdx.x * 256 + threadIdx.x;
    int total = H_HEADS * FH_DIM * NTP;
    #pragma unroll
    for (int j = 0; j < 8; ++j) {
        int e = i * 8 + j;
        if (e < total) vt[e] = __hip_bfloat16(0.0f);
    }
}

// ------------------------------------------------- weight f32->bf16 (x4) ----
__global__ void conv4_k(const float* __restrict__ s0, const float* __restrict__ s1,
                        const float* __restrict__ s2, const float* __restrict__ s3,
                        bf16* __restrict__ d0, bf16* __restrict__ d1,
                        bf16* __restrict__ d2, bf16* __restrict__ d3,
                        int c0, int c1, int c2, int c3) {
    int i = (blockIdx.x * 256 + threadIdx.x) * 4;
    const float* s; bf16* d; int off;
    if (i < c0)                { s = s0; d = d0; off = i; }
    else if (i < c0 + c1)      { s = s1; d = d1; off = i - c0; }
    else if (i < c0 + c1 + c2) { s = s2; d = d2; off = i - c0 - c1; }
    else if (i < c0 + c1 + c2 + c3) { s = s3; d = d3; off = i - c0 - c1 - c2; }
    else return;
    float4 v = *reinterpret_cast<const float4*>(s + off);
    ushort4 o;
    o.x = f2bf(v.x); o.y = f2bf(v.y); o.z = f2bf(v.z); o.w = f2bf(v.w);
    *reinterpret_cast<ushort4*>(d + off) = o;
}

// -------------------------------------------------------------- layernorm ----
__global__ void layernorm_k(const float* __restrict__ x, const float* __restrict__ w,
                            const float* __restrict__ b, bf16* __restrict__ out) {
    const int row = blockIdx.x;
    const float* xr = x + (size_t)row * F_DIM;
    float v0 = xr[threadIdx.x];
    float v1 = xr[threadIdx.x + 256];
    float v2 = xr[threadIdx.x + 512];
    float s  = v0 + v1 + v2;
    float s2 = v0 * v0 + v1 * v1 + v2 * v2;
    #pragma unroll
    for (int off = 32; off; off >>= 1) {
        s  += __shfl_down(s, off);
        s2 += __shfl_down(s2, off);
    }
    __shared__ float ws_[4], ws2_[4];
    int lane = threadIdx.x & 63, wid = threadIdx.x >> 6;
    if (lane == 0) { ws_[wid] = s; ws2_[wid] = s2; }
    __syncthreads();
    float S  = ws_[0] + ws_[1] + ws_[2] + ws_[3];
    float S2 = ws2_[0] + ws2_[1] + ws2_[2] + ws2_[3];
    float mu  = S * (1.0f / F_DIM);
    float var = S2 * (1.0f / F_DIM) - mu * mu;
    float rs  = rsqrtf(var + 1e-6f);
    bf16* orow = out + (size_t)row * F_DIM;
    orow[threadIdx.x]       = __hip_bfloat16((v0 - mu) * rs * w[threadIdx.x]       + b[threadIdx.x]);
    orow[threadIdx.x + 256] = __hip_bfloat16((v1 - mu) * rs * w[threadIdx.x + 256] + b[threadIdx.x + 256]);
    orow[threadIdx.x + 512] = __hip_bfloat16((v2 - mu) * rs * w[threadIdx.x + 512] + b[threadIdx.x + 512]);
}

// ------------------------------------------------------------- bf16 GEMM -----
// C[m][n] = sum_k A[m][k]*B[n][k], A: M x K (lda), B: Nc x K (ldb), both bf16.
// 128x128 tile, BK=32, 4 waves (2x2), each wave 64x64 = 4x4 frags of 16x16x32.
// EPI 0: QKV split   (p0=q_bias, p1=v_bias; outB0=q, outB1=k, outB2=vT)
// EPI 1: QK scores   (p0=table; rp; outF=attn; z=head)
// EPI 2: PV -> o_bf  (outB0=o_bf; z=head)
// EPI 3: residual    (p0=bias, p1=scale; outF=x, in-place)
// EPI 4: GELU        (p0=bias; outB0=m1_bf)

__device__ inline void stage_tile(const bf16* __restrict__ g0, int ld, int rows_rem,
                                  bf16* lds, int tid) {
    const int wbase = tid & ~63;          // wave-uniform part of slot index
    #pragma unroll
    for (int i = 0; i < 2; ++i) {
        int slot = i * 256 + tid;         // 16B slots: row = slot>>2, k16 = slot&3
        int row  = slot >> 2;
        int k16  = slot & 3;
        int grow = row < rows_rem ? row : (rows_rem - 1);
        const bf16* src = g0 + (size_t)grow * ld + k16 * 8;
        bf16* dst = lds + (size_t)(i * 256 + wbase) * 8;   // wave base; HW adds lane*16
        __builtin_amdgcn_global_load_lds((gptr_t)src, (lptr_t)dst, 16, 0, 0);
    }
}

template <int EPI>
__global__ __launch_bounds__(256)
void gemm_k(const bf16* __restrict__ A, const bf16* __restrict__ B,
            int M, int Nc, int K, int lda, int ldb,
            size_t aStrideZ, size_t bStrideZ,
            const float* __restrict__ p0, const float* __restrict__ p1,
            const int* __restrict__ rp,
            float* __restrict__ outF,
            bf16* __restrict__ outB0, bf16* __restrict__ outB1, bf16* __restrict__ outB2) {
    __shared__ __align__(16) bf16 As[128 * 32];
    __shared__ __align__(16) bf16 Bs[128 * 32];
    const int tid  = threadIdx.x;
    const int lane = tid & 63, wid = tid >> 6;
    const int wr = wid >> 1, wc = wid & 1;
    const int z  = blockIdx.z;
    const int bm = blockIdx.x * 128, bn = blockIdx.y * 128;
    const bf16* Ab = A + (size_t)z * aStrideZ + (size_t)bm * lda;
    const bf16* Bb = B + (size_t)z * bStrideZ + (size_t)bn * ldb;
    const int aRows = min(128, M - bm);
    const int bRows = min(128, Nc - bn);

    f32x4_t acc[4][4] = {};

    for (int k0 = 0; k0 < K; k0 += 32) {
        stage_tile(Ab + k0, lda, aRows, As, tid);
        stage_tile(Bb + k0, ldb, bRows, Bs, tid);
        __syncthreads();
        short8_t af[4], bfr[4];
        const short* AsS = reinterpret_cast<const short*>(As);
        const short* BsS = reinterpret_cast<const short*>(Bs);
        #pragma unroll
        for (int mi = 0; mi < 4; ++mi)
            af[mi] = *reinterpret_cast<const short8_t*>(
                AsS + (wr * 64 + mi * 16 + (lane & 15)) * 32 + (lane >> 4) * 8);
        #pragma unroll
        for (int ni = 0; ni < 4; ++ni)
            bfr[ni] = *reinterpret_cast<const short8_t*>(
                BsS + (wc * 64 + ni * 16 + (lane & 15)) * 32 + (lane >> 4) * 8);
        #pragma unroll
        for (int mi = 0; mi < 4; ++mi)
            #pragma unroll
            for (int ni = 0; ni < 4; ++ni)
                acc[mi][ni] = __builtin_amdgcn_mfma_f32_16x16x32_bf16(
                    af[mi], bfr[ni], acc[mi][ni], 0, 0, 0);
        __syncthreads();
    }

    #pragma unroll
    for (int mi = 0; mi < 4; ++mi) {
        #pragma unroll
        for (int r = 0; r < 4; ++r) {
            const int row = bm + wr * 64 + mi * 16 + (lane >> 4) * 4 + r;
            if (row >= M) continue;
            #pragma unroll
            for (int ni = 0; ni < 4; ++ni) {
                const int col = bn + wc * 64 + ni * 16 + (lane & 15);
                float v = acc[mi][ni][r];
                if (EPI == 0) {
                    // col in [0,2304): q | k | v
                    if (col < F_DIM) {
                        int h = col >> 6, d = col & 63;
                        float q = (v + p0[col]) * QK_SCALE;
                        outB0[((size_t)h * NT + row) * 64 + d] = __hip_bfloat16(q);
                    } else if (col < 2 * F_DIM) {
                        int g = col - F_DIM;
                        int h = g >> 6, d = g & 63;
                        outB1[((size_t)h * NT + row) * 64 + d] = __hip_bfloat16(v);
                    } else {
                        int g = col - 2 * F_DIM;
                        int h = g >> 6, d = g & 63;
                        float vv = v + p1[g];
                        outB2[((size_t)h * 64 + d) * NTP + row] = __hip_bfloat16(vv);
                    }
                } else if (EPI == 1) {
                    if (col < Nc) {
                        int idx = rp[(size_t)row * NT + col];
                        v += p0[(size_t)idx * H_HEADS + z];
                        outF[((size_t)z * NT + row) * NT + col] = v;
                    }
                } else if (EPI == 2) {
                    if (col < 64)
                        outB0[(size_t)row * F_DIM + z * 64 + col] = __hip_bfloat16(v);
                } else if (EPI == 3) {
                    size_t oi = (size_t)row * Nc + col;
                    v += p0[col];
                    outF[oi] = outF[oi] + p1[col] * v;
                } else if (EPI == 4) {
                    v += p0[col];
                    float g = 0.5f * v * (1.0f + erff(v * 0.70710678118654752f));
                    outB0[(size_t)row * MLPD + col] = __hip_bfloat16(g);
                }
            }
        }
    }
}

// ----------------------------------------------------------------- softmax ---
// read f32 scores row (NT), write bf16 probs row (NTP, zero tail)
__global__ void softmax_k(const float* __restrict__ attn, bf16* __restrict__ attn_bf) {
    const int row = blockIdx.x;           // h*NT + n
    const float* a = attn + (size_t)row * NT;
    const int h = row / NT, n = row - h * NT;
    bf16* o = attn_bf + ((size_t)h * NT + n) * NTP;
    float vals[5];
    float m = -1e30f;
    #pragma unroll
    for (int i = 0; i < 5; ++i) {
        int c = threadIdx.x + i * 256;
        vals[i] = (c < NT) ? a[c] : -1e30f;
        m = fmaxf(m, vals[i]);
    }
    #pragma unroll
    for (int off = 32; off; off >>= 1) m = fmaxf(m, __shfl_down(m, off));
    __shared__ float red[4];
    int lane = threadIdx.x & 63, wid = threadIdx.x >> 6;
    if (lane == 0) red[wid] = m;
    __syncthreads();
    m = fmaxf(fmaxf(red[0], red[1]), fmaxf(red[2], red[3]));
    float s = 0.0f;
    #pragma unroll
    for (int i = 0; i < 5; ++i) {
        int c = threadIdx.x + i * 256;
        if (c < NT) { vals[i] = __expf(vals[i] - m); s += vals[i]; }
    }
    #pragma unroll
    for (int off = 32; off; off >>= 1) s += __shfl_down(s, off);
    __syncthreads();
    if (lane == 0) red[wid] = s;
    __syncthreads();
    s = red[0] + red[1] + red[2] + red[3];
    float inv = 1.0f / s;
    #pragma unroll
    for (int i = 0; i < 5; ++i) {
        int c = threadIdx.x + i * 256;
        if (c < NT) o[c] = __hip_bfloat16(vals[i] * inv);
        else if (c < NTP) o[c] = __hip_bfloat16(0.0f);
    }
}

// ------------------------------------------------------------------- host ----
extern "C" void kernel_launch(void* const* d_in, const int* in_sizes, int n_in,
                              void* d_out, int out_size, void* d_ws, size_t ws_size,
                              hipStream_t stream) {
    const float* patch      = (const float*)d_in[0];
    const float* cls        = (const float*)d_in[1];
    const float* ln1_w      = (const float*)d_in[2];
    const float* ln1_b      = (const float*)d_in[3];
    const float* qkv_w      = (const float*)d_in[4];
    const float* q_bias     = (const float*)d_in[5];
    const float* v_bias     = (const float*)d_in[6];
    const float* proj_w     = (const float*)d_in[7];
    const float* proj_b     = (const float*)d_in[8];
    const float* scale_attn = (const float*)d_in[9];
    const float* ln2_w      = (const float*)d_in[10];
    const float* ln2_b      = (const float*)d_in[11];
    const float* fc1_w      = (const float*)d_in[12];
    const float* fc1_b      = (const float*)d_in[13];
    const float* fc2_w      = (const float*)d_in[14];
    const float* fc2_b      = (const float*)d_in[15];
    const float* scale_mlp  = (const float*)d_in[16];
    const float* table      = (const float*)d_in[17];
    const int*   rp_idx     = (const int*)d_in[18];
    float* out = (float*)d_out;

    char* ws = (char*)d_ws;
    size_t off = 0;
    auto alloc = [&](size_t bytes) { char* p = ws + off; off += (bytes + 255) & ~255ULL; return p; };

    float* x      = (float*)alloc((size_t)NT * F_DIM * 4);
    bf16*  h_bf   = (bf16*) alloc((size_t)NT * F_DIM * 2);
    bf16*  q_bf   = (bf16*) alloc((size_t)H_HEADS * NT * 64 * 2);
    bf16*  k_bf   = (bf16*) alloc((size_t)H_HEADS * NT * 64 * 2);
    bf16*  v_t    = (bf16*) alloc((size_t)H_HEADS * 64 * NTP * 2);
    bf16*  o_bf   = (bf16*) alloc((size_t)NT * F_DIM * 2);
    bf16*  m1_bf  = (bf16*) alloc((size_t)NT * MLPD * 2);
    float* attn   = (float*)alloc((size_t)H_HEADS * NT * NT * 4);
    bf16*  attnbf = (bf16*) alloc((size_t)H_HEADS * NT * NTP * 2);
    bf16*  wqkv   = (bf16*) alloc((size_t)THREE_F * F_DIM * 2);
    bf16*  wproj  = (bf16*) alloc((size_t)F_DIM * F_DIM * 2);
    bf16*  wfc1   = (bf16*) alloc((size_t)MLPD * F_DIM * 2);
    bf16*  wfc2   = (bf16*) alloc((size_t)F_DIM * MLPD * 2);

    const int cQKV = THREE_F * F_DIM, cPROJ = F_DIM * F_DIM;
    const int cFC1 = MLPD * F_DIM,    cFC2  = F_DIM * MLPD;
    const int convThreads = (cQKV + cPROJ + cFC1 + cFC2) / 4;

    init_x_k<<<(NT * F_DIM + 255) / 256, 256, 0, stream>>>(patch, cls, x);
    zero_vt_k<<<(H_HEADS * 64 * NTP + 2047) / 2048, 256, 0, stream>>>(v_t);

    int stage = 0;
    for (int l = 0; l < L_LAYERS; ++l) {
        conv4_k<<<(convThreads + 255) / 256, 256, 0, stream>>>(
            qkv_w + (size_t)l * cQKV, proj_w + (size_t)l * cPROJ,
            fc1_w + (size_t)l * cFC1, fc2_w + (size_t)l * cFC2,
            wqkv, wproj, wfc1, wfc2, cQKV, cPROJ, cFC1, cFC2);

        layernorm_k<<<NT, 256, 0, stream>>>(x, ln1_w + l * F_DIM, ln1_b + l * F_DIM, h_bf);

        // qkv: A = h_bf (NT x 768), B = wqkv (2304 x 768)
        gemm_k<0><<<dim3(9, 18), 256, 0, stream>>>(
            h_bf, wqkv, NT, THREE_F, F_DIM, F_DIM, F_DIM, 0, 0,
            q_bias + (size_t)l * F_DIM, v_bias + (size_t)l * F_DIM,
            nullptr, nullptr, q_bf, k_bf, v_t);

        // scores: per head, A = q (NT x 64), B = k (NT x 64)
        gemm_k<1><<<dim3(9, 9, H_HEADS), 256, 0, stream>>>(
            q_bf, k_bf, NT, NT, 64, 64, 64, (size_t)NT * 64, (size_t)NT * 64,
            table + (size_t)l * R_REL * H_HEADS, nullptr, rp_idx, attn,
            nullptr, nullptr, nullptr);

        softmax_k<<<H_HEADS * NT, 256, 0, stream>>>(attn, attnbf);

        // PV: per head, A = probs (NT x NTP), B = vT (64 x NTP)
        gemm_k<2><<<dim3(9, 1, H_HEADS), 256, 0, stream>>>(
            attnbf, v_t, NT, 64, NTP, NTP, NTP, (size_t)NT * NTP, (size_t)64 * NTP,
            nullptr, nullptr, nullptr, nullptr, o_bf, nullptr, nullptr);

        // proj + residual
        gemm_k<3><<<dim3(9, 6), 256, 0, stream>>>(
            o_bf, wproj, NT, F_DIM, F_DIM, F_DIM, F_DIM, 0, 0,
            proj_b + (size_t)l * F_DIM, scale_attn + (size_t)l * F_DIM,
            nullptr, x, nullptr, nullptr, nullptr);

        layernorm_k<<<NT, 256, 0, stream>>>(x, ln2_w + l * F_DIM, ln2_b + l * F_DIM, h_bf);

        // fc1 + gelu
        gemm_k<4><<<dim3(9, 24), 256, 0, stream>>>(
            h_bf, wfc1, NT, MLPD, F_DIM, F_DIM, F_DIM, 0, 0,
            fc1_b + (size_t)l * MLPD, nullptr,
            nullptr, nullptr, m1_bf, nullptr, nullptr);

        // fc2 + residual
        gemm_k<3><<<dim3(9, 6), 256, 0, stream>>>(
            m1_bf, wfc2, NT, F_DIM, MLPD, MLPD, MLPD, 0, 0,
            fc2_b + (size_t)l * F_DIM, scale_mlp + (size_t)l * F_DIM,
            nullptr, x, nullptr, nullptr, nullptr);

        if (l == 2 || l == 5 || l == 8 || l == 11) {
            (void)hipMemcpyAsync(out + (size_t)stage * NT * F_DIM, x,
                                 (size_t)NT * F_DIM * sizeof(float),
                                 hipMemcpyDeviceToDevice, stream);
            ++stage;
        }
    }
}

// Round 4
// 2922.141 us; speedup vs baseline: 5.9486x; 1.2258x over previous
//
#include <hip/hip_runtime.h>
#include <hip/hip_bf16.h>
#include <math.h>

#define L_LAYERS 12
#define H_HEADS  12
#define F_DIM    768
#define FH_DIM   64
#define MLPD     3072
#define NT       1025          // 1 + 32*32 tokens
#define NTP      1056          // NT padded to multiple of 32 (zero tail)
#define THREE_F  2304
#define R_REL    3972
#define QK_SCALE 0.125f
#define QB       64            // flash q-tile rows
#define KB       128           // flash kv-tile rows

typedef short short8_t __attribute__((ext_vector_type(8)));
typedef float f32x4_t  __attribute__((ext_vector_type(4)));
typedef __attribute__((address_space(1))) const void* gptr_t;
typedef __attribute__((address_space(3))) void*       lptr_t;

typedef __hip_bfloat16 bf16;

static __device__ inline unsigned short f2bf(float f) {
    __hip_bfloat16 b(f);
    unsigned short u;
    __builtin_memcpy(&u, &b, 2);
    return u;
}

// ---------------------------------------------------------------- init x ----
__global__ void init_x_k(const float* __restrict__ patch, const float* __restrict__ cls,
                         float* __restrict__ x) {
    int i = blockIdx.x * 256 + threadIdx.x;
    if (i >= NT * F_DIM) return;
    int n = i / F_DIM, f = i - n * F_DIM;
    x[i] = (n == 0) ? cls[f] : patch[(size_t)(n - 1) * F_DIM + f];
}

// ----------------------------------------------------------- zero vT tail ----
__global__ void zero_vt_k(bf16* __restrict__ vt) {
    int i = blockIdx.x * 256 + threadIdx.x;
    int total = H_HEADS * FH_DIM * NTP;
    #pragma unroll
    for (int j = 0; j < 8; ++j) {
        int e = i * 8 + j;
        if (e < total) vt[e] = __hip_bfloat16(0.0f);
    }
}

// ----------------------------------------------- rp_idx int32 -> uint16 -----
__global__ void rp16_k(const int* __restrict__ rp, unsigned short* __restrict__ rp16) {
    int i = blockIdx.x * 256 + threadIdx.x;
    if (i < NT * NT) rp16[i] = (unsigned short)rp[i];
}

// ------------------------------------- table [L][R][H] -> [L][H][R] f32 -----
__global__ void tableT_k(const float* __restrict__ t, float* __restrict__ tt) {
    int i = blockIdx.x * 256 + threadIdx.x;
    if (i >= L_LAYERS * R_REL * H_HEADS) return;
    int l = i / (R_REL * H_HEADS), rem = i - l * (R_REL * H_HEADS);
    int rr = rem / H_HEADS, hh = rem - rr * H_HEADS;
    tt[((size_t)l * H_HEADS + hh) * R_REL + rr] = t[i];
}

// ------------------------------------------------- weight f32->bf16 (x4) ----
__global__ void conv4_k(const float* __restrict__ s0, const float* __restrict__ s1,
                        const float* __restrict__ s2, const float* __restrict__ s3,
                        bf16* __restrict__ d0, bf16* __restrict__ d1,
                        bf16* __restrict__ d2, bf16* __restrict__ d3,
                        int c0, int c1, int c2, int c3) {
    int i = (blockIdx.x * 256 + threadIdx.x) * 4;
    const float* s; bf16* d; int off;
    if (i < c0)                { s = s0; d = d0; off = i; }
    else if (i < c0 + c1)      { s = s1; d = d1; off = i - c0; }
    else if (i < c0 + c1 + c2) { s = s2; d = d2; off = i - c0 - c1; }
    else if (i < c0 + c1 + c2 + c3) { s = s3; d = d3; off = i - c0 - c1 - c2; }
    else return;
    float4 v = *reinterpret_cast<const float4*>(s + off);
    ushort4 o;
    o.x = f2bf(v.x); o.y = f2bf(v.y); o.z = f2bf(v.z); o.w = f2bf(v.w);
    *reinterpret_cast<ushort4*>(d + off) = o;
}

// -------------------------------------------------------------- layernorm ----
__global__ void layernorm_k(const float* __restrict__ x, const float* __restrict__ w,
                            const float* __restrict__ b, bf16* __restrict__ out) {
    const int row = blockIdx.x;
    const float* xr = x + (size_t)row * F_DIM;
    float v0 = xr[threadIdx.x];
    float v1 = xr[threadIdx.x + 256];
    float v2 = xr[threadIdx.x + 512];
    float s  = v0 + v1 + v2;
    float s2 = v0 * v0 + v1 * v1 + v2 * v2;
    #pragma unroll
    for (int off = 32; off; off >>= 1) {
        s  += __shfl_down(s, off);
        s2 += __shfl_down(s2, off);
    }
    __shared__ float ws_[4], ws2_[4];
    int lane = threadIdx.x & 63, wid = threadIdx.x >> 6;
    if (lane == 0) { ws_[wid] = s; ws2_[wid] = s2; }
    __syncthreads();
    float S  = ws_[0] + ws_[1] + ws_[2] + ws_[3];
    float S2 = ws2_[0] + ws2_[1] + ws2_[2] + ws2_[3];
    float mu  = S * (1.0f / F_DIM);
    float var = S2 * (1.0f / F_DIM) - mu * mu;
    float rs  = rsqrtf(var + 1e-6f);
    bf16* orow = out + (size_t)row * F_DIM;
    orow[threadIdx.x]       = __hip_bfloat16((v0 - mu) * rs * w[threadIdx.x]       + b[threadIdx.x]);
    orow[threadIdx.x + 256] = __hip_bfloat16((v1 - mu) * rs * w[threadIdx.x + 256] + b[threadIdx.x + 256]);
    orow[threadIdx.x + 512] = __hip_bfloat16((v2 - mu) * rs * w[threadIdx.x + 512] + b[threadIdx.x + 512]);
}

// ------------------------------------------------------------- bf16 GEMM -----
// C[m][n] = sum_k A[m][k]*B[n][k].  128x128 tile, BK=32, 4 waves.
// EPI 0: QKV split (p0=q_bias, p1=v_bias; outB0=q, outB1=k, outB2=vT)
// EPI 3: residual  (p0=bias, p1=scale; outF=x, in-place)
// EPI 4: GELU      (p0=bias; outB0=m1_bf)
__device__ inline void stage_tile(const bf16* __restrict__ g0, int ld, int rows_rem,
                                  bf16* lds, int tid) {
    const int wbase = tid & ~63;
    #pragma unroll
    for (int i = 0; i < 2; ++i) {
        int slot = i * 256 + tid;
        int row  = slot >> 2;
        int k16  = slot & 3;
        int grow = row < rows_rem ? row : (rows_rem - 1);
        const bf16* src = g0 + (size_t)grow * ld + k16 * 8;
        bf16* dst = lds + (size_t)(i * 256 + wbase) * 8;
        __builtin_amdgcn_global_load_lds((gptr_t)src, (lptr_t)dst, 16, 0, 0);
    }
}

template <int EPI>
__global__ __launch_bounds__(256)
void gemm_k(const bf16* __restrict__ A, const bf16* __restrict__ B,
            int M, int Nc, int K, int lda, int ldb,
            const float* __restrict__ p0, const float* __restrict__ p1,
            float* __restrict__ outF,
            bf16* __restrict__ outB0, bf16* __restrict__ outB1, bf16* __restrict__ outB2) {
    __shared__ __align__(16) bf16 As[128 * 32];
    __shared__ __align__(16) bf16 Bs[128 * 32];
    const int tid  = threadIdx.x;
    const int lane = tid & 63, wid = tid >> 6;
    const int wr = wid >> 1, wc = wid & 1;
    const int bm = blockIdx.x * 128, bn = blockIdx.y * 128;
    const bf16* Ab = A + (size_t)bm * lda;
    const bf16* Bb = B + (size_t)bn * ldb;
    const int aRows = min(128, M - bm);
    const int bRows = min(128, Nc - bn);

    f32x4_t acc[4][4] = {};

    for (int k0 = 0; k0 < K; k0 += 32) {
        stage_tile(Ab + k0, lda, aRows, As, tid);
        stage_tile(Bb + k0, ldb, bRows, Bs, tid);
        __syncthreads();
        short8_t af[4], bfr[4];
        const short* AsS = reinterpret_cast<const short*>(As);
        const short* BsS = reinterpret_cast<const short*>(Bs);
        #pragma unroll
        for (int mi = 0; mi < 4; ++mi)
            af[mi] = *reinterpret_cast<const short8_t*>(
                AsS + (wr * 64 + mi * 16 + (lane & 15)) * 32 + (lane >> 4) * 8);
        #pragma unroll
        for (int ni = 0; ni < 4; ++ni)
            bfr[ni] = *reinterpret_cast<const short8_t*>(
                BsS + (wc * 64 + ni * 16 + (lane & 15)) * 32 + (lane >> 4) * 8);
        #pragma unroll
        for (int mi = 0; mi < 4; ++mi)
            #pragma unroll
            for (int ni = 0; ni < 4; ++ni)
                acc[mi][ni] = __builtin_amdgcn_mfma_f32_16x16x32_bf16(
                    af[mi], bfr[ni], acc[mi][ni], 0, 0, 0);
        __syncthreads();
    }

    #pragma unroll
    for (int mi = 0; mi < 4; ++mi) {
        #pragma unroll
        for (int r = 0; r < 4; ++r) {
            const int row = bm + wr * 64 + mi * 16 + (lane >> 4) * 4 + r;
            if (row >= M) continue;
            #pragma unroll
            for (int ni = 0; ni < 4; ++ni) {
                const int col = bn + wc * 64 + ni * 16 + (lane & 15);
                float v = acc[mi][ni][r];
                if (EPI == 0) {
                    if (col < F_DIM) {
                        int h = col >> 6, d = col & 63;
                        float q = (v + p0[col]) * QK_SCALE;
                        outB0[((size_t)h * NT + row) * 64 + d] = __hip_bfloat16(q);
                    } else if (col < 2 * F_DIM) {
                        int g = col - F_DIM;
                        int h = g >> 6, d = g & 63;
                        outB1[((size_t)h * NT + row) * 64 + d] = __hip_bfloat16(v);
                    } else {
                        int g = col - 2 * F_DIM;
                        int h = g >> 6, d = g & 63;
                        float vv = v + p1[g];
                        outB2[((size_t)h * 64 + d) * NTP + row] = __hip_bfloat16(vv);
                    }
                } else if (EPI == 3) {
                    size_t oi = (size_t)row * Nc + col;
                    v += p0[col];
                    outF[oi] = outF[oi] + p1[col] * v;
                } else if (EPI == 4) {
                    v += p0[col];
                    float g = 0.5f * v * (1.0f + erff(v * 0.70710678118654752f));
                    outB0[(size_t)row * MLPD + col] = __hip_bfloat16(g);
                }
            }
        }
    }
}

// ------------------------------------------------------- fused attention ----
// grid (ceil(NT/QB), H).  Block = 4 waves; wave w owns q-rows [qb+16w, +16).
// Online softmax over KV tiles of KB=128.  All LDS tiles XOR-swizzled
// (pre-swizzled global source for global_load_lds; swizzled ds reads).
__global__ __launch_bounds__(256)
void flash_k(const bf16* __restrict__ q_bf, const bf16* __restrict__ k_bf,
             const bf16* __restrict__ v_t, const unsigned short* __restrict__ rp16,
             const float* __restrict__ tableT, bf16* __restrict__ o_bf) {
    __shared__ __align__(16) bf16 Qs[QB * 64];
    __shared__ __align__(16) bf16 Ks[KB * 64];
    __shared__ __align__(16) bf16 Vs[64 * KB];
    __shared__ __align__(16) bf16 Ps[4][16 * KB];

    const int tid = threadIdx.x, lane = tid & 63, w = tid >> 6;
    const int h  = blockIdx.y;
    const int qb = blockIdx.x * QB;
    const bf16* qh = q_bf + (size_t)h * NT * 64;
    const bf16* kh = k_bf + (size_t)h * NT * 64;
    const bf16* vh = v_t  + (size_t)h * 64 * NTP;
    const float* tbl = tableT + (size_t)h * R_REL;
    const int q_local = lane & 15;
    const int g4 = lane >> 4;             // 0..3

    // ---- stage Q tile (QB x 64), swizzle slot ^= row&7 on the SOURCE ----
    {
        const int qRows = min(QB, NT - qb);
        #pragma unroll
        for (int i = 0; i < 2; ++i) {     // QB*8/256
            int slot = i * 256 + tid;
            int row = slot >> 3, s = slot & 7;
            int grow = min(row, qRows - 1);
            const bf16* src = qh + (size_t)(qb + grow) * 64 + (s ^ (row & 7)) * 8;
            bf16* dst = Qs + (size_t)(i * 256 + (tid & ~63)) * 8;
            __builtin_amdgcn_global_load_lds((gptr_t)src, (lptr_t)dst, 16, 0, 0);
        }
    }
    __syncthreads();

    short8_t qf[2];
    {
        const short* QsS = (const short*)Qs;
        #pragma unroll
        for (int kk = 0; kk < 2; ++kk) {
            int row = w * 16 + q_local;
            int slot = (kk * 4 + g4) ^ (row & 7);
            qf[kk] = *(const short8_t*)(QsS + row * 64 + slot * 8);
        }
    }

    float m_run[4], l_run[4];
    f32x4_t acc[4] = {};
    #pragma unroll
    for (int r = 0; r < 4; ++r) { m_run[r] = -1e30f; l_run[r] = 0.0f; }

    for (int m0 = 0; m0 < NT; m0 += KB) {
        // ---- stage K (KB x 64) and V^T (64 x KB) ----
        const int kRows = min(KB, NT - m0);
        #pragma unroll
        for (int i = 0; i < 4; ++i) {     // KB*8/256
            int slot = i * 256 + tid;
            int row = slot >> 3, s = slot & 7;
            int grow = min(row, kRows - 1);
            const bf16* src = kh + (size_t)(m0 + grow) * 64 + (s ^ (row & 7)) * 8;
            bf16* dst = Ks + (size_t)(i * 256 + (tid & ~63)) * 8;
            __builtin_amdgcn_global_load_lds((gptr_t)src, (lptr_t)dst, 16, 0, 0);
        }
        #pragma unroll
        for (int i = 0; i < 4; ++i) {     // 64*16/256
            int slot = i * 256 + tid;
            int d = slot >> 4, s = slot & 15;
            int msl = min(m0 / 8 + (s ^ (d & 15)), NTP / 8 - 1);
            const bf16* src = vh + (size_t)d * NTP + msl * 8;
            bf16* dst = Vs + (size_t)(i * 256 + (tid & ~63)) * 8;
            __builtin_amdgcn_global_load_lds((gptr_t)src, (lptr_t)dst, 16, 0, 0);
        }
        __syncthreads();

        // ---- S = Q K^T (wave's 16 rows x 128 cols) ----
        f32x4_t sfr[8];
        {
            const short* KsS = (const short*)Ks;
            #pragma unroll
            for (int f = 0; f < 8; ++f) {
                f32x4_t c = {};
                #pragma unroll
                for (int kk = 0; kk < 2; ++kk) {
                    int mrow = f * 16 + q_local;
                    int slot = (kk * 4 + g4) ^ (mrow & 7);
                    short8_t bv = *(const short8_t*)(KsS + mrow * 64 + slot * 8);
                    c = __builtin_amdgcn_mfma_f32_16x16x32_bf16(qf[kk], bv, c, 0, 0, 0);
                }
                sfr[f] = c;
            }
        }

        // ---- + relpos bias, mask tail ----
        const int qrow_base = qb + w * 16 + g4 * 4;
        #pragma unroll
        for (int f = 0; f < 8; ++f) {
            int mm = m0 + f * 16 + q_local;
            if (mm < NT) {
                #pragma unroll
                for (int r = 0; r < 4; ++r) {
                    int qc = min(qrow_base + r, NT - 1);
                    int idx = rp16[(size_t)qc * NT + mm];
                    sfr[f][r] += tbl[idx];
                }
            } else {
                #pragma unroll
                for (int r = 0; r < 4; ++r) sfr[f][r] = -1e30f;
            }
        }

        // ---- online softmax ----
        float pmax[4];
        #pragma unroll
        for (int r = 0; r < 4; ++r) {
            float mx = sfr[0][r];
            #pragma unroll
            for (int f = 1; f < 8; ++f) mx = fmaxf(mx, sfr[f][r]);
            pmax[r] = mx;
        }
        #pragma unroll
        for (int off = 1; off < 16; off <<= 1)
            #pragma unroll
            for (int r = 0; r < 4; ++r) pmax[r] = fmaxf(pmax[r], __shfl_xor(pmax[r], off));

        float fac[4];
        #pragma unroll
        for (int r = 0; r < 4; ++r) {
            float mnew = fmaxf(m_run[r], pmax[r]);
            fac[r] = __expf(m_run[r] - mnew);
            m_run[r] = mnew;
        }

        float rsum[4] = {0.f, 0.f, 0.f, 0.f};
        short* PsW = (short*)Ps[w];
        #pragma unroll
        for (int f = 0; f < 8; ++f) {
            int mloc = f * 16 + q_local;
            #pragma unroll
            for (int r = 0; r < 4; ++r) {
                int ql = g4 * 4 + r;
                float p = __expf(sfr[f][r] - m_run[r]);
                rsum[r] += p;
                PsW[ql * 128 + (((mloc >> 3) ^ ql) * 8) + (mloc & 7)] = (short)f2bf(p);
            }
        }
        #pragma unroll
        for (int off = 1; off < 16; off <<= 1)
            #pragma unroll
            for (int r = 0; r < 4; ++r) rsum[r] += __shfl_xor(rsum[r], off);
        #pragma unroll
        for (int r = 0; r < 4; ++r) l_run[r] = l_run[r] * fac[r] + rsum[r];
        #pragma unroll
        for (int df = 0; df < 4; ++df)
            #pragma unroll
            for (int r = 0; r < 4; ++r) acc[df][r] *= fac[r];

        // ---- PV: O += P V ----
        {
            const short* PsR = (const short*)Ps[w];
            const short* VsS = (const short*)Vs;
            #pragma unroll
            for (int kk = 0; kk < 4; ++kk) {
                int j = kk * 4 + g4;
                short8_t pa = *(const short8_t*)(PsR + q_local * 128 + (j ^ q_local) * 8);
                #pragma unroll
                for (int df = 0; df < 4; ++df) {
                    int drow = df * 16 + q_local;
                    short8_t vb = *(const short8_t*)(VsS + drow * 128 + (j ^ (drow & 15)) * 8);
                    acc[df] = __builtin_amdgcn_mfma_f32_16x16x32_bf16(pa, vb, acc[df], 0, 0, 0);
                }
            }
        }
        __syncthreads();
    }

    // ---- epilogue: O /= l, store ----
    #pragma unroll
    for (int df = 0; df < 4; ++df) {
        #pragma unroll
        for (int r = 0; r < 4; ++r) {
            int qq = qb + w * 16 + g4 * 4 + r;
            if (qq < NT) {
                float o = acc[df][r] / l_run[r];
                o_bf[(size_t)qq * F_DIM + h * 64 + df * 16 + q_local] = __hip_bfloat16(o);
            }
        }
    }
}

// ------------------------------------------------------------------- host ----
extern "C" void kernel_launch(void* const* d_in, const int* in_sizes, int n_in,
                              void* d_out, int out_size, void* d_ws, size_t ws_size,
                              hipStream_t stream) {
    const float* patch      = (const float*)d_in[0];
    const float* cls        = (const float*)d_in[1];
    const float* ln1_w      = (const float*)d_in[2];
    const float* ln1_b      = (const float*)d_in[3];
    const float* qkv_w      = (const float*)d_in[4];
    const float* q_bias     = (const float*)d_in[5];
    const float* v_bias     = (const float*)d_in[6];
    const float* proj_w     = (const float*)d_in[7];
    const float* proj_b     = (const float*)d_in[8];
    const float* scale_attn = (const float*)d_in[9];
    const float* ln2_w      = (const float*)d_in[10];
    const float* ln2_b      = (const float*)d_in[11];
    const float* fc1_w      = (const float*)d_in[12];
    const float* fc1_b      = (const float*)d_in[13];
    const float* fc2_w      = (const float*)d_in[14];
    const float* fc2_b      = (const float*)d_in[15];
    const float* scale_mlp  = (const float*)d_in[16];
    const float* table      = (const float*)d_in[17];
    const int*   rp_idx     = (const int*)d_in[18];
    float* out = (float*)d_out;

    char* ws = (char*)d_ws;
    size_t off = 0;
    auto alloc = [&](size_t bytes) { char* p = ws + off; off += (bytes + 255) & ~255ULL; return p; };

    float* x      = (float*)alloc((size_t)NT * F_DIM * 4);
    bf16*  h_bf   = (bf16*) alloc((size_t)NT * F_DIM * 2);
    bf16*  q_bf   = (bf16*) alloc((size_t)H_HEADS * NT * 64 * 2);
    bf16*  k_bf   = (bf16*) alloc((size_t)H_HEADS * NT * 64 * 2);
    bf16*  v_t    = (bf16*) alloc((size_t)H_HEADS * 64 * NTP * 2);
    bf16*  o_bf   = (bf16*) alloc((size_t)NT * F_DIM * 2);
    bf16*  m1_bf  = (bf16*) alloc((size_t)NT * MLPD * 2);
    bf16*  wqkv   = (bf16*) alloc((size_t)THREE_F * F_DIM * 2);
    bf16*  wproj  = (bf16*) alloc((size_t)F_DIM * F_DIM * 2);
    bf16*  wfc1   = (bf16*) alloc((size_t)MLPD * F_DIM * 2);
    bf16*  wfc2   = (bf16*) alloc((size_t)F_DIM * MLPD * 2);
    unsigned short* rp16 = (unsigned short*)alloc((size_t)NT * NT * 2);
    float* tableT = (float*)alloc((size_t)L_LAYERS * H_HEADS * R_REL * 4);

    const int cQKV = THREE_F * F_DIM, cPROJ = F_DIM * F_DIM;
    const int cFC1 = MLPD * F_DIM,    cFC2  = F_DIM * MLPD;
    const int convThreads = (cQKV + cPROJ + cFC1 + cFC2) / 4;

    init_x_k<<<(NT * F_DIM + 255) / 256, 256, 0, stream>>>(patch, cls, x);
    zero_vt_k<<<(H_HEADS * 64 * NTP + 2047) / 2048, 256, 0, stream>>>(v_t);
    rp16_k<<<(NT * NT + 255) / 256, 256, 0, stream>>>(rp_idx, rp16);
    tableT_k<<<(L_LAYERS * R_REL * H_HEADS + 255) / 256, 256, 0, stream>>>(table, tableT);

    int stage = 0;
    for (int l = 0; l < L_LAYERS; ++l) {
        conv4_k<<<(convThreads + 255) / 256, 256, 0, stream>>>(
            qkv_w + (size_t)l * cQKV, proj_w + (size_t)l * cPROJ,
            fc1_w + (size_t)l * cFC1, fc2_w + (size_t)l * cFC2,
            wqkv, wproj, wfc1, wfc2, cQKV, cPROJ, cFC1, cFC2);

        layernorm_k<<<NT, 256, 0, stream>>>(x, ln1_w + l * F_DIM, ln1_b + l * F_DIM, h_bf);

        gemm_k<0><<<dim3(9, 18), 256, 0, stream>>>(
            h_bf, wqkv, NT, THREE_F, F_DIM, F_DIM, F_DIM,
            q_bias + (size_t)l * F_DIM, v_bias + (size_t)l * F_DIM,
            nullptr, q_bf, k_bf, v_t);

        flash_k<<<dim3((NT + QB - 1) / QB, H_HEADS), 256, 0, stream>>>(
            q_bf, k_bf, v_t, rp16,
            tableT + (size_t)l * H_HEADS * R_REL, o_bf);

        gemm_k<3><<<dim3(9, 6), 256, 0, stream>>>(
            o_bf, wproj, NT, F_DIM, F_DIM, F_DIM, F_DIM,
            proj_b + (size_t)l * F_DIM, scale_attn + (size_t)l * F_DIM,
            x, nullptr, nullptr, nullptr);

        layernorm_k<<<NT, 256, 0, stream>>>(x, ln2_w + l * F_DIM, ln2_b + l * F_DIM, h_bf);

        gemm_k<4><<<dim3(9, 24), 256, 0, stream>>>(
            h_bf, wfc1, NT, MLPD, F_DIM, F_DIM, F_DIM,
            fc1_b + (size_t)l * MLPD, nullptr,
            nullptr, m1_bf, nullptr, nullptr);

        gemm_k<3><<<dim3(9, 6), 256, 0, stream>>>(
            m1_bf, wfc2, NT, F_DIM, MLPD, MLPD, MLPD,
            fc2_b + (size_t)l * F_DIM, scale_mlp + (size_t)l * F_DIM,
            x, nullptr, nullptr, nullptr);

        if (l == 2 || l == 5 || l == 8 || l == 11) {
            (void)hipMemcpyAsync(out + (size_t)stage * NT * F_DIM, x,
                                 (size_t)NT * F_DIM * sizeof(float),
                                 hipMemcpyDeviceToDevice, stream);
            ++stage;
        }
    }
}

// Round 5
// 1890.005 us; speedup vs baseline: 9.1971x; 1.5461x over previous
//
#include <hip/hip_runtime.h>
#include <hip/hip_bf16.h>
#include <math.h>

#define L_LAYERS 12
#define H_HEADS  12
#define F_DIM    768
#define FH_DIM   64
#define MLPD     3072
#define NT       1025          // 1 + 32*32 tokens
#define NTP      1056          // NT padded to multiple of 32 (zero tail)
#define THREE_F  2304
#define R_REL    3972
#define QK_SCALE 0.125f
#define QB       64            // flash q-tile rows
#define KB       128           // flash kv-tile rows

typedef short short8_t __attribute__((ext_vector_type(8)));
typedef float f32x4_t  __attribute__((ext_vector_type(4)));
typedef __attribute__((address_space(1))) const void* gptr_t;
typedef __attribute__((address_space(3))) void*       lptr_t;

typedef __hip_bfloat16 bf16;

static __device__ inline unsigned short f2bf(float f) {
    __hip_bfloat16 b(f);
    unsigned short u;
    __builtin_memcpy(&u, &b, 2);
    return u;
}

// bijective 8-way XCD chunking over the y-major linearized tile list (m204).
// Blocks with the same y-tile (same B weight panel) land on the same XCD.
__device__ inline void xcd_remap(int& tx, int& ty) {
    int gx = gridDim.x, gy = gridDim.y;
    int b = blockIdx.y * gx + blockIdx.x;
    int total = gx * gy;
    int q = total >> 3, r = total & 7;
    int xcd = b & 7, i = b >> 3;
    int pos = (xcd < r) ? xcd * (q + 1) + i : r * (q + 1) + (xcd - r) * q + i;
    ty = pos / gx;
    tx = pos - ty * gx;
}

// ---------------------------------------------------------------- init x ----
__global__ void init_x_k(const float* __restrict__ patch, const float* __restrict__ cls,
                         float* __restrict__ x) {
    int i = blockIdx.x * 256 + threadIdx.x;
    if (i >= NT * F_DIM) return;
    int n = i / F_DIM, f = i - n * F_DIM;
    x[i] = (n == 0) ? cls[f] : patch[(size_t)(n - 1) * F_DIM + f];
}

// ----------------------------------------------------------- zero vT tail ----
__global__ void zero_vt_k(bf16* __restrict__ vt) {
    int i = blockIdx.x * 256 + threadIdx.x;
    int total = H_HEADS * FH_DIM * NTP;
    #pragma unroll
    for (int j = 0; j < 8; ++j) {
        int e = i * 8 + j;
        if (e < total) vt[e] = __hip_bfloat16(0.0f);
    }
}

// ----------------------------------------------- rp_idx int32 -> uint16 -----
__global__ void rp16_k(const int* __restrict__ rp, unsigned short* __restrict__ rp16) {
    int i = blockIdx.x * 256 + threadIdx.x;
    if (i < NT * NT) rp16[i] = (unsigned short)rp[i];
}

// ------------------------------------- table [L][R][H] -> [L][H][R] f32 -----
__global__ void tableT_k(const float* __restrict__ t, float* __restrict__ tt) {
    int i = blockIdx.x * 256 + threadIdx.x;
    if (i >= L_LAYERS * R_REL * H_HEADS) return;
    int l = i / (R_REL * H_HEADS), rem = i - l * (R_REL * H_HEADS);
    int rr = rem / H_HEADS, hh = rem - rr * H_HEADS;
    tt[((size_t)l * H_HEADS + hh) * R_REL + rr] = t[i];
}

// ------------------------------------------------- weight f32->bf16 (x4) ----
__global__ void conv4_k(const float* __restrict__ s0, const float* __restrict__ s1,
                        const float* __restrict__ s2, const float* __restrict__ s3,
                        bf16* __restrict__ d0, bf16* __restrict__ d1,
                        bf16* __restrict__ d2, bf16* __restrict__ d3,
                        int c0, int c1, int c2, int c3) {
    int i = (blockIdx.x * 256 + threadIdx.x) * 4;
    const float* s; bf16* d; int off;
    if (i < c0)                { s = s0; d = d0; off = i; }
    else if (i < c0 + c1)      { s = s1; d = d1; off = i - c0; }
    else if (i < c0 + c1 + c2) { s = s2; d = d2; off = i - c0 - c1; }
    else if (i < c0 + c1 + c2 + c3) { s = s3; d = d3; off = i - c0 - c1 - c2; }
    else return;
    float4 v = *reinterpret_cast<const float4*>(s + off);
    ushort4 o;
    o.x = f2bf(v.x); o.y = f2bf(v.y); o.z = f2bf(v.z); o.w = f2bf(v.w);
    *reinterpret_cast<ushort4*>(d + off) = o;
}

// -------------------------------------------------------------- layernorm ----
__global__ void layernorm_k(const float* __restrict__ x, const float* __restrict__ w,
                            const float* __restrict__ b, bf16* __restrict__ out) {
    const int row = blockIdx.x;
    const float* xr = x + (size_t)row * F_DIM;
    float v0 = xr[threadIdx.x];
    float v1 = xr[threadIdx.x + 256];
    float v2 = xr[threadIdx.x + 512];
    float s  = v0 + v1 + v2;
    float s2 = v0 * v0 + v1 * v1 + v2 * v2;
    #pragma unroll
    for (int off = 32; off; off >>= 1) {
        s  += __shfl_down(s, off);
        s2 += __shfl_down(s2, off);
    }
    __shared__ float ws_[4], ws2_[4];
    int lane = threadIdx.x & 63, wid = threadIdx.x >> 6;
    if (lane == 0) { ws_[wid] = s; ws2_[wid] = s2; }
    __syncthreads();
    float S  = ws_[0] + ws_[1] + ws_[2] + ws_[3];
    float S2 = ws2_[0] + ws2_[1] + ws2_[2] + ws2_[3];
    float mu  = S * (1.0f / F_DIM);
    float var = S2 * (1.0f / F_DIM) - mu * mu;
    float rs  = rsqrtf(var + 1e-6f);
    bf16* orow = out + (size_t)row * F_DIM;
    orow[threadIdx.x]       = __hip_bfloat16((v0 - mu) * rs * w[threadIdx.x]       + b[threadIdx.x]);
    orow[threadIdx.x + 256] = __hip_bfloat16((v1 - mu) * rs * w[threadIdx.x + 256] + b[threadIdx.x + 256]);
    orow[threadIdx.x + 512] = __hip_bfloat16((v2 - mu) * rs * w[threadIdx.x + 512] + b[threadIdx.x + 512]);
}

// ------------------------------------------------------------- bf16 GEMM -----
// C[m][n] = sum_k A[m][k]*B[n][k].  BM=64, BN=128, BK=64, 512 threads (8 waves
// 2x4, wave tile 32x32 = 2x2 frags).  XOR-swizzled LDS staging (pre-swizzled
// global source, linear LDS dest).
// EPI 0: QKV split (p0=q_bias, p1=v_bias; outB0=q, outB1=k, outB2=vT)
// EPI 3: residual  (p0=bias, p1=scale; outF=x, in-place)
// EPI 4: GELU      (p0=bias; outB0=m1_bf)

// stage R x 64 bf16 tile; NLOAD = R*8/512 loads/thread; swizzle slot^=(row&7)
template <int R, int NLOAD>
__device__ inline void stage64(const bf16* __restrict__ g0, int ld, int rows_rem,
                               bf16* lds, int tid) {
    #pragma unroll
    for (int i = 0; i < NLOAD; ++i) {
        int slot = i * 512 + tid;
        int row = slot >> 3, s = slot & 7;
        int grow = row < rows_rem ? row : (rows_rem - 1);
        const bf16* src = g0 + (size_t)grow * ld + ((s ^ (row & 7)) * 8);
        bf16* dst = lds + (size_t)(i * 512 + (tid & ~63)) * 8;
        __builtin_amdgcn_global_load_lds((gptr_t)src, (lptr_t)dst, 16, 0, 0);
    }
}

template <int EPI>
__global__ __launch_bounds__(512)
void gemm_k(const bf16* __restrict__ A, const bf16* __restrict__ B,
            int M, int Nc, int K, int lda, int ldb,
            const float* __restrict__ p0, const float* __restrict__ p1,
            float* __restrict__ outF,
            bf16* __restrict__ outB0, bf16* __restrict__ outB1, bf16* __restrict__ outB2) {
    __shared__ __align__(16) bf16 As[64 * 64];
    __shared__ __align__(16) bf16 Bs[128 * 64];
    int tx, ty;
    xcd_remap(tx, ty);
    const int tid  = threadIdx.x;
    const int lane = tid & 63, wid = tid >> 6;
    const int wr = wid >> 2, wc = wid & 3;          // 2 x 4 waves
    const int g4 = lane >> 4, l16 = lane & 15;
    const int bm = tx * 64, bn = ty * 128;
    const bf16* Ab = A + (size_t)bm * lda;
    const bf16* Bb = B + (size_t)bn * ldb;
    const int aRows = min(64, M - bm);

    f32x4_t acc[2][2] = {};

    for (int k0 = 0; k0 < K; k0 += 64) {
        stage64<64, 1>(Ab + k0, lda, aRows, As, tid);
        stage64<128, 2>(Bb + k0, ldb, 128, Bs, tid);
        __syncthreads();
        const short* AsS = reinterpret_cast<const short*>(As);
        const short* BsS = reinterpret_cast<const short*>(Bs);
        #pragma unroll
        for (int kk = 0; kk < 2; ++kk) {
            short8_t af[2], bfr[2];
            #pragma unroll
            for (int mi = 0; mi < 2; ++mi) {
                int ar = wr * 32 + mi * 16 + l16;
                int js = (kk * 4 + g4) ^ (ar & 7);
                af[mi] = *reinterpret_cast<const short8_t*>(AsS + ar * 64 + js * 8);
            }
            #pragma unroll
            for (int ni = 0; ni < 2; ++ni) {
                int br = wc * 32 + ni * 16 + l16;
                int js = (kk * 4 + g4) ^ (br & 7);
                bfr[ni] = *reinterpret_cast<const short8_t*>(BsS + br * 64 + js * 8);
            }
            #pragma unroll
            for (int mi = 0; mi < 2; ++mi)
                #pragma unroll
                for (int ni = 0; ni < 2; ++ni)
                    acc[mi][ni] = __builtin_amdgcn_mfma_f32_16x16x32_bf16(
                        af[mi], bfr[ni], acc[mi][ni], 0, 0, 0);
        }
        __syncthreads();
    }

    #pragma unroll
    for (int mi = 0; mi < 2; ++mi) {
        #pragma unroll
        for (int r = 0; r < 4; ++r) {
            const int row = bm + wr * 32 + mi * 16 + g4 * 4 + r;
            if (row >= M) continue;
            #pragma unroll
            for (int ni = 0; ni < 2; ++ni) {
                const int col = bn + wc * 32 + ni * 16 + l16;
                float v = acc[mi][ni][r];
                if (EPI == 0) {
                    if (col < F_DIM) {
                        int h = col >> 6, d = col & 63;
                        float q = (v + p0[col]) * QK_SCALE;
                        outB0[((size_t)h * NT + row) * 64 + d] = __hip_bfloat16(q);
                    } else if (col < 2 * F_DIM) {
                        int g = col - F_DIM;
                        int h = g >> 6, d = g & 63;
                        outB1[((size_t)h * NT + row) * 64 + d] = __hip_bfloat16(v);
                    } else {
                        int g = col - 2 * F_DIM;
                        int h = g >> 6, d = g & 63;
                        float vv = v + p1[g];
                        outB2[((size_t)h * 64 + d) * NTP + row] = __hip_bfloat16(vv);
                    }
                } else if (EPI == 3) {
                    size_t oi = (size_t)row * Nc + col;
                    v += p0[col];
                    outF[oi] = outF[oi] + p1[col] * v;
                } else if (EPI == 4) {
                    v += p0[col];
                    float g = 0.5f * v * (1.0f + erff(v * 0.70710678118654752f));
                    outB0[(size_t)row * MLPD + col] = __hip_bfloat16(g);
                }
            }
        }
    }
}

// ------------------------------------------------------- fused attention ----
// grid (17, H).  Block = 4 waves; wave w owns q-rows [qb+16w, +16).
// Online softmax over KV tiles of KB=128.
__global__ __launch_bounds__(256)
void flash_k(const bf16* __restrict__ q_bf, const bf16* __restrict__ k_bf,
             const bf16* __restrict__ v_t, const unsigned short* __restrict__ rp16,
             const float* __restrict__ tableT, bf16* __restrict__ o_bf) {
    __shared__ __align__(16) bf16 Qs[QB * 64];
    __shared__ __align__(16) bf16 Ks[KB * 64];
    __shared__ __align__(16) bf16 Vs[64 * KB];
    __shared__ __align__(16) bf16 Ps[4][16 * KB];

    int qx, h;
    xcd_remap(qx, h);                    // y-major grouping: same head -> same XCD
    const int tid = threadIdx.x, lane = tid & 63, w = tid >> 6;
    const int qb = qx * QB;
    const bf16* qh = q_bf + (size_t)h * NT * 64;
    const bf16* kh = k_bf + (size_t)h * NT * 64;
    const bf16* vh = v_t  + (size_t)h * 64 * NTP;
    const float* tbl = tableT + (size_t)h * R_REL;
    const int q_local = lane & 15;
    const int g4 = lane >> 4;             // 0..3

    {
        const int qRows = min(QB, NT - qb);
        #pragma unroll
        for (int i = 0; i < 2; ++i) {
            int slot = i * 256 + tid;
            int row = slot >> 3, s = slot & 7;
            int grow = min(row, qRows - 1);
            const bf16* src = qh + (size_t)(qb + grow) * 64 + (s ^ (row & 7)) * 8;
            bf16* dst = Qs + (size_t)(i * 256 + (tid & ~63)) * 8;
            __builtin_amdgcn_global_load_lds((gptr_t)src, (lptr_t)dst, 16, 0, 0);
        }
    }
    __syncthreads();

    short8_t qf[2];
    {
        const short* QsS = (const short*)Qs;
        #pragma unroll
        for (int kk = 0; kk < 2; ++kk) {
            int row = w * 16 + q_local;
            int slot = (kk * 4 + g4) ^ (row & 7);
            qf[kk] = *(const short8_t*)(QsS + row * 64 + slot * 8);
        }
    }

    float m_run[4], l_run[4];
    f32x4_t acc[4] = {};
    #pragma unroll
    for (int r = 0; r < 4; ++r) { m_run[r] = -1e30f; l_run[r] = 0.0f; }

    for (int m0 = 0; m0 < NT; m0 += KB) {
        const int kRows = min(KB, NT - m0);
        #pragma unroll
        for (int i = 0; i < 4; ++i) {
            int slot = i * 256 + tid;
            int row = slot >> 3, s = slot & 7;
            int grow = min(row, kRows - 1);
            const bf16* src = kh + (size_t)(m0 + grow) * 64 + (s ^ (row & 7)) * 8;
            bf16* dst = Ks + (size_t)(i * 256 + (tid & ~63)) * 8;
            __builtin_amdgcn_global_load_lds((gptr_t)src, (lptr_t)dst, 16, 0, 0);
        }
        #pragma unroll
        for (int i = 0; i < 4; ++i) {
            int slot = i * 256 + tid;
            int d = slot >> 4, s = slot & 15;
            int msl = min(m0 / 8 + (s ^ (d & 15)), NTP / 8 - 1);
            const bf16* src = vh + (size_t)d * NTP + msl * 8;
            bf16* dst = Vs + (size_t)(i * 256 + (tid & ~63)) * 8;
            __builtin_amdgcn_global_load_lds((gptr_t)src, (lptr_t)dst, 16, 0, 0);
        }
        __syncthreads();

        f32x4_t sfr[8];
        {
            const short* KsS = (const short*)Ks;
            #pragma unroll
            for (int f = 0; f < 8; ++f) {
                f32x4_t c = {};
                #pragma unroll
                for (int kk = 0; kk < 2; ++kk) {
                    int mrow = f * 16 + q_local;
                    int slot = (kk * 4 + g4) ^ (mrow & 7);
                    short8_t bv = *(const short8_t*)(KsS + mrow * 64 + slot * 8);
                    c = __builtin_amdgcn_mfma_f32_16x16x32_bf16(qf[kk], bv, c, 0, 0, 0);
                }
                sfr[f] = c;
            }
        }

        const int qrow_base = qb + w * 16 + g4 * 4;
        #pragma unroll
        for (int f = 0; f < 8; ++f) {
            int mm = m0 + f * 16 + q_local;
            if (mm < NT) {
                #pragma unroll
                for (int r = 0; r < 4; ++r) {
                    int qc = min(qrow_base + r, NT - 1);
                    int idx = rp16[(size_t)qc * NT + mm];
                    sfr[f][r] += tbl[idx];
                }
            } else {
                #pragma unroll
                for (int r = 0; r < 4; ++r) sfr[f][r] = -1e30f;
            }
        }

        float pmax[4];
        #pragma unroll
        for (int r = 0; r < 4; ++r) {
            float mx = sfr[0][r];
            #pragma unroll
            for (int f = 1; f < 8; ++f) mx = fmaxf(mx, sfr[f][r]);
            pmax[r] = mx;
        }
        #pragma unroll
        for (int off = 1; off < 16; off <<= 1)
            #pragma unroll
            for (int r = 0; r < 4; ++r) pmax[r] = fmaxf(pmax[r], __shfl_xor(pmax[r], off));

        float fac[4];
        #pragma unroll
        for (int r = 0; r < 4; ++r) {
            float mnew = fmaxf(m_run[r], pmax[r]);
            fac[r] = __expf(m_run[r] - mnew);
            m_run[r] = mnew;
        }

        float rsum[4] = {0.f, 0.f, 0.f, 0.f};
        short* PsW = (short*)Ps[w];
        #pragma unroll
        for (int f = 0; f < 8; ++f) {
            int mloc = f * 16 + q_local;
            #pragma unroll
            for (int r = 0; r < 4; ++r) {
                int ql = g4 * 4 + r;
                float p = __expf(sfr[f][r] - m_run[r]);
                rsum[r] += p;
                PsW[ql * 128 + (((mloc >> 3) ^ ql) * 8) + (mloc & 7)] = (short)f2bf(p);
            }
        }
        #pragma unroll
        for (int off = 1; off < 16; off <<= 1)
            #pragma unroll
            for (int r = 0; r < 4; ++r) rsum[r] += __shfl_xor(rsum[r], off);
        #pragma unroll
        for (int r = 0; r < 4; ++r) l_run[r] = l_run[r] * fac[r] + rsum[r];
        #pragma unroll
        for (int df = 0; df < 4; ++df)
            #pragma unroll
            for (int r = 0; r < 4; ++r) acc[df][r] *= fac[r];

        {
            const short* PsR = (const short*)Ps[w];
            const short* VsS = (const short*)Vs;
            #pragma unroll
            for (int kk = 0; kk < 4; ++kk) {
                int j = kk * 4 + g4;
                short8_t pa = *(const short8_t*)(PsR + q_local * 128 + (j ^ q_local) * 8);
                #pragma unroll
                for (int df = 0; df < 4; ++df) {
                    int drow = df * 16 + q_local;
                    short8_t vb = *(const short8_t*)(VsS + drow * 128 + (j ^ (drow & 15)) * 8);
                    acc[df] = __builtin_amdgcn_mfma_f32_16x16x32_bf16(pa, vb, acc[df], 0, 0, 0);
                }
            }
        }
        __syncthreads();
    }

    #pragma unroll
    for (int df = 0; df < 4; ++df) {
        #pragma unroll
        for (int r = 0; r < 4; ++r) {
            int qq = qb + w * 16 + g4 * 4 + r;
            if (qq < NT) {
                float o = acc[df][r] / l_run[r];
                o_bf[(size_t)qq * F_DIM + h * 64 + df * 16 + q_local] = __hip_bfloat16(o);
            }
        }
    }
}

// ------------------------------------------------------------------- host ----
extern "C" void kernel_launch(void* const* d_in, const int* in_sizes, int n_in,
                              void* d_out, int out_size, void* d_ws, size_t ws_size,
                              hipStream_t stream) {
    const float* patch      = (const float*)d_in[0];
    const float* cls        = (const float*)d_in[1];
    const float* ln1_w      = (const float*)d_in[2];
    const float* ln1_b      = (const float*)d_in[3];
    const float* qkv_w      = (const float*)d_in[4];
    const float* q_bias     = (const float*)d_in[5];
    const float* v_bias     = (const float*)d_in[6];
    const float* proj_w     = (const float*)d_in[7];
    const float* proj_b     = (const float*)d_in[8];
    const float* scale_attn = (const float*)d_in[9];
    const float* ln2_w      = (const float*)d_in[10];
    const float* ln2_b      = (const float*)d_in[11];
    const float* fc1_w      = (const float*)d_in[12];
    const float* fc1_b      = (const float*)d_in[13];
    const float* fc2_w      = (const float*)d_in[14];
    const float* fc2_b      = (const float*)d_in[15];
    const float* scale_mlp  = (const float*)d_in[16];
    const float* table      = (const float*)d_in[17];
    const int*   rp_idx     = (const int*)d_in[18];
    float* out = (float*)d_out;

    char* ws = (char*)d_ws;
    size_t off = 0;
    auto alloc = [&](size_t bytes) { char* p = ws + off; off += (bytes + 255) & ~255ULL; return p; };

    float* x      = (float*)alloc((size_t)NT * F_DIM * 4);
    bf16*  h_bf   = (bf16*) alloc((size_t)NT * F_DIM * 2);
    bf16*  q_bf   = (bf16*) alloc((size_t)H_HEADS * NT * 64 * 2);
    bf16*  k_bf   = (bf16*) alloc((size_t)H_HEADS * NT * 64 * 2);
    bf16*  v_t    = (bf16*) alloc((size_t)H_HEADS * 64 * NTP * 2);
    bf16*  o_bf   = (bf16*) alloc((size_t)NT * F_DIM * 2);
    bf16*  m1_bf  = (bf16*) alloc((size_t)NT * MLPD * 2);
    bf16*  wqkv   = (bf16*) alloc((size_t)THREE_F * F_DIM * 2);
    bf16*  wproj  = (bf16*) alloc((size_t)F_DIM * F_DIM * 2);
    bf16*  wfc1   = (bf16*) alloc((size_t)MLPD * F_DIM * 2);
    bf16*  wfc2   = (bf16*) alloc((size_t)F_DIM * MLPD * 2);
    unsigned short* rp16 = (unsigned short*)alloc((size_t)NT * NT * 2);
    float* tableT = (float*)alloc((size_t)L_LAYERS * H_HEADS * R_REL * 4);

    const int cQKV = THREE_F * F_DIM, cPROJ = F_DIM * F_DIM;
    const int cFC1 = MLPD * F_DIM,    cFC2  = F_DIM * MLPD;
    const int convThreads = (cQKV + cPROJ + cFC1 + cFC2) / 4;

    init_x_k<<<(NT * F_DIM + 255) / 256, 256, 0, stream>>>(patch, cls, x);
    zero_vt_k<<<(H_HEADS * 64 * NTP + 2047) / 2048, 256, 0, stream>>>(v_t);
    rp16_k<<<(NT * NT + 255) / 256, 256, 0, stream>>>(rp_idx, rp16);
    tableT_k<<<(L_LAYERS * R_REL * H_HEADS + 255) / 256, 256, 0, stream>>>(table, tableT);

    int stage = 0;
    for (int l = 0; l < L_LAYERS; ++l) {
        conv4_k<<<(convThreads + 255) / 256, 256, 0, stream>>>(
            qkv_w + (size_t)l * cQKV, proj_w + (size_t)l * cPROJ,
            fc1_w + (size_t)l * cFC1, fc2_w + (size_t)l * cFC2,
            wqkv, wproj, wfc1, wfc2, cQKV, cPROJ, cFC1, cFC2);

        layernorm_k<<<NT, 256, 0, stream>>>(x, ln1_w + l * F_DIM, ln1_b + l * F_DIM, h_bf);

        gemm_k<0><<<dim3(17, 18), 512, 0, stream>>>(
            h_bf, wqkv, NT, THREE_F, F_DIM, F_DIM, F_DIM,
            q_bias + (size_t)l * F_DIM, v_bias + (size_t)l * F_DIM,
            nullptr, q_bf, k_bf, v_t);

        flash_k<<<dim3((NT + QB - 1) / QB, H_HEADS), 256, 0, stream>>>(
            q_bf, k_bf, v_t, rp16,
            tableT + (size_t)l * H_HEADS * R_REL, o_bf);

        gemm_k<3><<<dim3(17, 6), 512, 0, stream>>>(
            o_bf, wproj, NT, F_DIM, F_DIM, F_DIM, F_DIM,
            proj_b + (size_t)l * F_DIM, scale_attn + (size_t)l * F_DIM,
            x, nullptr, nullptr, nullptr);

        layernorm_k<<<NT, 256, 0, stream>>>(x, ln2_w + l * F_DIM, ln2_b + l * F_DIM, h_bf);

        gemm_k<4><<<dim3(17, 24), 512, 0, stream>>>(
            h_bf, wfc1, NT, MLPD, F_DIM, F_DIM, F_DIM,
            fc1_b + (size_t)l * MLPD, nullptr,
            nullptr, m1_bf, nullptr, nullptr);

        gemm_k<3><<<dim3(17, 6), 512, 0, stream>>>(
            m1_bf, wfc2, NT, F_DIM, MLPD, MLPD, MLPD,
            fc2_b + (size_t)l * F_DIM, scale_mlp + (size_t)l * F_DIM,
            x, nullptr, nullptr, nullptr);

        if (l == 2 || l == 5 || l == 8 || l == 11) {
            (void)hipMemcpyAsync(out + (size_t)stage * NT * F_DIM, x,
                                 (size_t)NT * F_DIM * sizeof(float),
                                 hipMemcpyDeviceToDevice, stream);
            ++stage;
        }
    }
}